// Round 8
// baseline (174.833 us; speedup 1.0000x reference)
//
#include <hip/hip_runtime.h>

#define NVEC 65536   // B*H*W = 64*32*32
#define KC   1024
#define DD   64
#define NTILE 64     // n per block (lane = n)
#define KSPLIT 2     // k-split across blockIdx.y
#define KW   128     // k per wave  (KSPLIT * 4 waves * KW = 1024)
#define KU   32      // k-unroll (accs per lane)

// d_out layout (f32): [0]=loss, [1..4194305)=z_q (B,D,H,W), [4194305]=perplexity, [4194306..)=idx
#define OUT_ZQ   1
#define OUT_PPL  4194305
#define OUT_IDX  4194306

// ws layout (bytes)
#define WS_KEYS  0          // u64[NVEC]      = 524288
#define WS_HIST  524288     // int[KC]        = 4096
#define WS_SUMSQ 528384     // double         = 8
#define WS_SE    528392     // float[KC]      = 4096
#define WS_EMBT  532488     // float[DD*KC]   = 262144  (embT[c][k])
// sz[NVEC] lives in the z_q output region (out+OUT_ZQ), fully overwritten by
// the epilogue afterwards -- no extra ws needed.

// prep_z: sz[n] = np.sum(zf**2, axis=1), numpy pairwise order (verified bit-exact R2)
__global__ __launch_bounds__(256) void prep_z(const float* __restrict__ z,
                                              float* __restrict__ sz) {
    const int n  = blockIdx.x * 256 + threadIdx.x;
    const int b  = n >> 10;
    const int hw = n & 1023;
    const float* zp = z + (size_t)b * 65536 + hw;   // stride 1024 over c, lane-coalesced
    float r[8];
    #pragma unroll
    for (int c = 0; c < 64; ++c) {
        float v = zp[(size_t)c * 1024];
        float s = __fmul_rn(v, v);
        if (c < 8) r[c] = s;
        else       r[c & 7] = __fadd_rn(r[c & 7], s);
    }
    sz[n] = __fadd_rn(__fadd_rn(__fadd_rn(r[0], r[1]), __fadd_rn(r[2], r[3])),
                      __fadd_rn(__fadd_rn(r[4], r[5]), __fadd_rn(r[6], r[7])));
}

// prep_emb: se[k] (numpy pairwise, verified) + embT[c][k] global transpose.
__global__ __launch_bounds__(256) void prep_emb(const float* __restrict__ emb,
                                                float* __restrict__ se,
                                                float* __restrict__ embT) {
    __shared__ float tile[64][65];
    const int tid = threadIdx.x;
    const int k0  = blockIdx.x * 64;
    {
        const int r = tid >> 2, q = tid & 3;
        const float* row = emb + (size_t)(k0 + r) * 64 + q * 16;
        #pragma unroll
        for (int i = 0; i < 4; ++i) {
            float4 v = *(const float4*)(row + i * 4);
            tile[r][q * 16 + i * 4 + 0] = v.x;
            tile[r][q * 16 + i * 4 + 1] = v.y;
            tile[r][q * 16 + i * 4 + 2] = v.z;
            tile[r][q * 16 + i * 4 + 3] = v.w;
        }
    }
    __syncthreads();
    if (tid < 64) {
        float r[8];
        #pragma unroll
        for (int c = 0; c < 64; ++c) {
            float v = tile[tid][c];
            float s = __fmul_rn(v, v);
            if (c < 8) r[c] = s;
            else       r[c & 7] = __fadd_rn(r[c & 7], s);
        }
        se[k0 + tid] = __fadd_rn(
            __fadd_rn(__fadd_rn(r[0], r[1]), __fadd_rn(r[2], r[3])),
            __fadd_rn(__fadd_rn(r[4], r[5]), __fadd_rn(r[6], r[7])));
    }
    const int kl = tid & 63, cg = tid >> 6;
    #pragma unroll
    for (int i = 0; i < 16; ++i) {
        int c = cg * 16 + i;
        embT[(size_t)c * KC + k0 + kl] = tile[kl][c];
    }
}

// dist: lane = n, zero LDS. z per-lane from global (vmcnt, L1-resident 16KB/block);
// e wave-uniform from embT via s_load (lgkmcnt) -> independent counters, both
// streams prefetchable. Wave owns 64n x 128k; KU=32 accs.
// Per (n,k): sequential __fmaf_rn over c=0..63, then d = fmaf(-2,acc,fadd(sz,se))
// -- bit-identical to the verified chain. k ascending + strict '<' =>
// numpy first-index tie-break; cross-block merge via (monotone<<10|k) atomicMin.
__global__ __launch_bounds__(256)
void dist_kernel(const float* __restrict__ z,
                 const float* __restrict__ embT,
                 const float* __restrict__ se,
                 const float* __restrict__ sz,
                 unsigned long long* __restrict__ keys) {
    const int tid  = threadIdx.x;
    const int lane = tid & 63;
    const int n0   = blockIdx.x * NTILE;
    const int b    = n0 >> 10;
    const int hw0  = n0 & 1023;
    const int n    = n0 + lane;

    const float szn = sz[n];
    const int   kb  = __builtin_amdgcn_readfirstlane(
                          (blockIdx.y * 4 + (tid >> 6)) * KW);

    const float* __restrict__ zbase = z + (size_t)b * 65536 + hw0 + lane;

    float dbest  = 3.4e38f;
    int   kbestv = 0;

    for (int g = 0; g < KW; g += KU) {
        const int kg = kb + g;                       // uniform
        float acc[KU];
        #pragma unroll
        for (int j = 0; j < KU; ++j) acc[j] = 0.0f;

        #pragma unroll 4
        for (int c = 0; c < 64; ++c) {
            const float zc = zbase[(size_t)c * 1024];                  // VMEM, coalesced
            const float* __restrict__ eb = embT + (size_t)c * KC + kg; // uniform -> s_load
            #pragma unroll
            for (int j = 0; j < KU; ++j)
                acc[j] = __fmaf_rn(zc, eb[j], acc[j]);
        }

        const float* __restrict__ sb = se + kg;      // uniform
        #pragma unroll
        for (int j = 0; j < KU; ++j) {
            float d = __fmaf_rn(-2.0f, acc[j], __fadd_rn(szn, sb[j]));
            if (d < dbest) { dbest = d; kbestv = kg + j; }   // ascending k, strict <
        }
    }

    unsigned m = __float_as_uint(dbest);
    m ^= ((int)m < 0) ? 0xFFFFFFFFu : 0x80000000u;
    atomicMin(&keys[n], ((unsigned long long)m << 10) | (unsigned)kbestv);
}

__global__ __launch_bounds__(256) void epilogue_kernel(const float* __restrict__ z,
                                                       const float* __restrict__ emb,
                                                       const unsigned long long* __restrict__ keys,
                                                       float* __restrict__ out,
                                                       int* __restrict__ hist,
                                                       double* __restrict__ sumsq) {
    __shared__ double red[256];
    const int tid = threadIdx.x;
    const int n   = blockIdx.x * 256 + tid;
    const int b   = n >> 10;
    const int hw  = n & 1023;
    const int idx = (int)(keys[n] & 1023ULL);

    out[OUT_IDX + n] = (float)idx;
    atomicAdd(&hist[idx], 1);

    const float* zp = z   + (size_t)b * 65536 + hw;
    float*       op = out + OUT_ZQ + (size_t)b * 65536 + hw;
    const float* er = emb + (size_t)idx * DD;
    double s = 0.0;
    #pragma unroll
    for (int c = 0; c < DD; ++c) {
        float zv   = zp[(size_t)c * 1024];
        float ev   = er[c];
        float diff = ev - zv;                  // z_q - z
        op[(size_t)c * 1024] = zv + diff;      // straight-through
        s = fma((double)diff, (double)diff, s);
    }
    red[tid] = s;
    __syncthreads();
    for (int off = 128; off > 0; off >>= 1) {
        if (tid < off) red[tid] += red[tid + off];
        __syncthreads();
    }
    if (tid == 0) atomicAdd(sumsq, red[0]);
}

__global__ __launch_bounds__(256) void final_kernel(const int* __restrict__ hist,
                                                    const double* __restrict__ sumsq,
                                                    float* __restrict__ out) {
    __shared__ double red[256];
    const int tid = threadIdx.x;
    double s = 0.0;
    #pragma unroll
    for (int j = 0; j < 4; ++j) {
        int   kk = j * 256 + tid;
        float em = (float)hist[kk] * (1.0f / 65536.0f);
        float t  = em * logf(em + 1e-10f);
        s += (double)t;
    }
    red[tid] = s;
    __syncthreads();
    for (int off = 128; off > 0; off >>= 1) {
        if (tid < off) red[tid] += red[tid + off];
        __syncthreads();
    }
    if (tid == 0) {
        out[OUT_PPL] = expf(-(float)red[0]);
        out[0]       = 1.25f * (float)(sumsq[0] / 4194304.0);
    }
}

extern "C" void kernel_launch(void* const* d_in, const int* in_sizes, int n_in,
                              void* d_out, int out_size, void* d_ws, size_t ws_size,
                              hipStream_t stream) {
    const float* z   = (const float*)d_in[0];
    const float* emb = (const float*)d_in[1];
    float* out = (float*)d_out;
    char*  ws  = (char*)d_ws;

    unsigned long long* keys  = (unsigned long long*)(ws + WS_KEYS);
    int*                hist  = (int*)(ws + WS_HIST);
    double*             sumsq = (double*)(ws + WS_SUMSQ);
    float*              se    = (float*)(ws + WS_SE);
    float*              embT  = (float*)(ws + WS_EMBT);
    float*              sz    = out + OUT_ZQ;   // scratch; epilogue overwrites z_q later

    hipMemsetAsync(keys, 0xFF, (size_t)NVEC * 8, stream);
    hipMemsetAsync(hist, 0, (size_t)KC * 4 + 8, stream);  // hist + sumsq contiguous

    prep_z  <<<NVEC / 256, 256, 0, stream>>>(z, sz);
    prep_emb<<<KC / 64,    256, 0, stream>>>(emb, se, embT);
    dist_kernel<<<dim3(NVEC / NTILE, KSPLIT), 256, 0, stream>>>(z, embT, se, sz, keys);
    epilogue_kernel<<<NVEC / 256, 256, 0, stream>>>(z, emb, keys, out, hist, sumsq);
    final_kernel<<<1, 256, 0, stream>>>(hist, sumsq, out);
}